// Round 7
// baseline (453.580 us; speedup 1.0000x reference)
//
#include <hip/hip_runtime.h>
#include <stdint.h>

#define SEQ 2048
#define DM  2048
#define NH  32
#define HDIM 64

typedef unsigned short u16;
typedef short bf16x8 __attribute__((ext_vector_type(8)));
typedef float f32x4 __attribute__((ext_vector_type(4)));

__device__ __forceinline__ u16 f2bf(float f) {
    union { float f; uint32_t u; } v; v.f = f;
    uint32_t u = v.u;
    uint32_t r = (u + 0x7fffu + ((u >> 16) & 1u)) >> 16;
    return (u16)r;
}

// async global->LDS, 16B per lane. LDS dest is wave-uniform base + lane*16.
#define GLOAD_LDS16(g, l) __builtin_amdgcn_global_load_lds( \
    (const __attribute__((address_space(1))) uint32_t*)(g), \
    (__attribute__((address_space(3))) uint32_t*)(l), 16, 0, 0)

// ---------------- fp32 -> bf16 conversion; z>0 are measurement dups ----------
__global__ __launch_bounds__(256) void cvt_bf16(
    const float* __restrict__ X, const float* __restrict__ Wq,
    const float* __restrict__ Wk, const float* __restrict__ Wv,
    const float* __restrict__ Wo,
    u16* __restrict__ Xb, u16* __restrict__ Wqb, u16* __restrict__ Wkb,
    u16* __restrict__ Wvb, u16* __restrict__ Wob, u16* __restrict__ dummy)
{
    const int NV = (DM * SEQ) / 4;   // float4 count per 2048x2048 array
    int arr = blockIdx.y;
    int dup = blockIdx.z;            // 0 = real, >0 = duplicate (dead dest)
    const float4* s; u16* d;
    switch (arr) {
        case 0:  s = (const float4*)X;  d = Xb;  break;
        case 1:  s = (const float4*)Wq; d = Wqb; break;
        case 2:  s = (const float4*)Wk; d = Wkb; break;
        case 3:  s = (const float4*)Wv; d = Wvb; break;
        default: s = (const float4*)Wo; d = Wob; break;
    }
    if (dup) d = dummy;              // races between dups: dead scratch, fine
    for (int i = blockIdx.x * blockDim.x + threadIdx.x; i < NV; i += gridDim.x * blockDim.x) {
        float4 v = s[i];
        ushort4 o;
        o.x = f2bf(v.x); o.y = f2bf(v.y); o.z = f2bf(v.z); o.w = f2bf(v.w);
        *(ushort4*)(d + i * 4) = o;
    }
}

// ---------------- gates GEMM: Fpart[kp][h][s] = X[s,kp-part] . Wf[h,kp-part] --
__global__ __launch_bounds__(256) void gates_gemm(
    const float* __restrict__ X, const float* __restrict__ Wf,
    float* __restrict__ Fpart, float* __restrict__ FpartDummy)
{
    __shared__ float lX[64 * 68];
    __shared__ float lW[32 * 68];
    int s0 = blockIdx.x * 64;
    int kp = blockIdx.y;
    float* Fout = blockIdx.z ? FpartDummy : Fpart;
    int tid = threadIdx.x;
    int h = tid & 31, sg = tid >> 5;     // s-group 0..7
    float acc[8] = {0.f,0.f,0.f,0.f,0.f,0.f,0.f,0.f};
    for (int k0 = kp * 128; k0 < kp * 128 + 128; k0 += 64) {
        __syncthreads();
        {
            int r = tid >> 2, seg = tid & 3;
            const float4* src = (const float4*)(X + (size_t)(s0 + r) * DM + k0);
            float4* dst = (float4*)(&lX[r * 68]);
#pragma unroll
            for (int i = 0; i < 4; i++) dst[seg + 4 * i] = src[seg + 4 * i];
#pragma unroll
            for (int j = 0; j < 2; j++) {
                int ii = tid + j * 256;
                int wr_ = ii >> 4, wc_ = ii & 15;
                ((float4*)(&lW[wr_ * 68]))[wc_] =
                    ((const float4*)(Wf + (size_t)wr_ * DM + k0))[wc_];
            }
        }
        __syncthreads();
#pragma unroll
        for (int k4 = 0; k4 < 16; k4++) {
            float4 w = ((const float4*)(&lW[h * 68]))[k4];
#pragma unroll
            for (int i = 0; i < 8; i++) {
                float4 x = ((const float4*)(&lX[(sg + 8 * i) * 68]))[k4];
                acc[i] += x.x * w.x + x.y * w.y + x.z * w.z + x.w * w.w;
            }
        }
    }
#pragma unroll
    for (int i = 0; i < 8; i++)
        Fout[(size_t)kp * NH * SEQ + h * SEQ + s0 + sg + 8 * i] = acc[i];
}

// ------- reduce k-partials, logsigmoid(+bias), cumulative sum; 1 block/head --
__global__ __launch_bounds__(256) void gates_scan(
    const float* __restrict__ Fpart, float* __restrict__ F,
    const float* __restrict__ bfp)
{
    __shared__ float lws[4];
    int h = blockIdx.x;
    int tid = threadIdx.x;
    int lane = tid & 63, wv = tid >> 6;
    float bb = bfp[h];
    float v[8] = {0.f,0.f,0.f,0.f,0.f,0.f,0.f,0.f};
#pragma unroll
    for (int kp = 0; kp < 16; kp++) {
        const float4* src = (const float4*)(Fpart + (size_t)kp * NH * SEQ + (size_t)h * SEQ);
        float4 a = src[tid * 2], b2 = src[tid * 2 + 1];
        v[0] += a.x;  v[1] += a.y;  v[2] += a.z;  v[3] += a.w;
        v[4] += b2.x; v[5] += b2.y; v[6] += b2.z; v[7] += b2.w;
    }
#pragma unroll
    for (int i = 0; i < 8; i++) {
        float g = v[i] + bb;
        v[i] = fminf(g, 0.f) - log1pf(expf(-fabsf(g)));
    }
#pragma unroll
    for (int i = 1; i < 8; i++) v[i] += v[i - 1];
    float tsum = v[7];
    float sc = tsum;
#pragma unroll
    for (int d = 1; d < 64; d <<= 1) {
        float t = __shfl_up(sc, d);
        if (lane >= d) sc += t;
    }
    if (lane == 63) lws[wv] = sc;
    __syncthreads();
    float woff = 0.f;
#pragma unroll
    for (int w2 = 0; w2 < 4; w2++) if (w2 < wv) woff += lws[w2];
    float off = woff + sc - tsum;
#pragma unroll
    for (int i = 0; i < 8; i++) v[i] += off;
    float4 o1 = {v[0], v[1], v[2], v[3]}, o2 = {v[4], v[5], v[6], v[7]};
    ((float4*)(F + (size_t)h * SEQ))[tid * 2] = o1;
    ((float4*)(F + (size_t)h * SEQ))[tid * 2 + 1] = o2;
}

// ---------------- QKV GEMM: {Q,K,V}[m][n] = sum_k X[m][k] * W{q,k,v}[n][k] ----
// z==2 (V) writes TRANSPOSED output Vt[d2][s].
__global__ __launch_bounds__(256, 3) void gemm_qkv(
    const u16* __restrict__ A,
    const u16* __restrict__ B0, const u16* __restrict__ B1, const u16* __restrict__ B2,
    u16* __restrict__ C0, u16* __restrict__ C1, u16* __restrict__ C2)
{
    __shared__ u16 lA[128 * 32];
    __shared__ u16 lB[128 * 32];
    const int K = DM, N = DM;
    int z = blockIdx.z;
    const u16* Bm = (z == 0) ? B0 : ((z == 1) ? B1 : B2);
    u16* Cm = (z == 0) ? C0 : ((z == 1) ? C1 : C2);
    int m0 = blockIdx.y * 128, n0 = blockIdx.x * 128;
    int tid = threadIdx.x;
    int wave = tid >> 6, lane = tid & 63, ln = lane & 15, quad = lane >> 4;
    int wr = (wave >> 1) * 64, wc = (wave & 1) * 64;

    f32x4 acc[4][4];
#pragma unroll
    for (int i = 0; i < 4; i++)
#pragma unroll
        for (int j = 0; j < 4; j++)
#pragma unroll
            for (int r = 0; r < 4; r++) acc[i][j][r] = 0.f;

    int srow = wave * 32 + (lane >> 2);
    int scol = (lane & 3) * 8;
    const u16* gA0 = &A[(size_t)(m0 + srow) * K + scol];
    const u16* gA1 = &A[(size_t)(m0 + srow + 16) * K + scol];
    const u16* gB0 = &Bm[(size_t)(n0 + srow) * K + scol];
    const u16* gB1 = &Bm[(size_t)(n0 + srow + 16) * K + scol];
    u16* dA0 = &lA[(wave * 32) * 32];
    u16* dA1 = &lA[(wave * 32 + 16) * 32];
    u16* dB0 = &lB[(wave * 32) * 32];
    u16* dB1 = &lB[(wave * 32 + 16) * 32];

    for (int kk0 = 0; kk0 < K / 32; kk0++) {
        __syncthreads();
        GLOAD_LDS16(gA0, dA0);
        GLOAD_LDS16(gA1, dA1);
        GLOAD_LDS16(gB0, dB0);
        GLOAD_LDS16(gB1, dB1);
        gA0 += 32; gA1 += 32; gB0 += 32; gB1 += 32;
        __syncthreads();
        bf16x8 af[4], bfr[4];
#pragma unroll
        for (int i = 0; i < 4; i++) af[i]  = *(const bf16x8*)(&lA[(wr + i * 16 + ln) * 32 + quad * 8]);
#pragma unroll
        for (int j = 0; j < 4; j++) bfr[j] = *(const bf16x8*)(&lB[(wc + j * 16 + ln) * 32 + quad * 8]);
#pragma unroll
        for (int i = 0; i < 4; i++)
#pragma unroll
            for (int j = 0; j < 4; j++)
                acc[i][j] = __builtin_amdgcn_mfma_f32_16x16x32_bf16(af[i], bfr[j], acc[i][j], 0, 0, 0);
    }

    if (z == 2) {
#pragma unroll
        for (int i = 0; i < 4; i++)
#pragma unroll
            for (int j = 0; j < 4; j++) {
                int col = n0 + wc + j * 16 + ln;
                int row0 = m0 + wr + i * 16 + quad * 4;
                ushort4 pk;
                pk.x = f2bf(acc[i][j][0]); pk.y = f2bf(acc[i][j][1]);
                pk.z = f2bf(acc[i][j][2]); pk.w = f2bf(acc[i][j][3]);
                *(ushort4*)(&Cm[(size_t)col * SEQ + row0]) = pk;
            }
    } else {
#pragma unroll
        for (int i = 0; i < 4; i++)
#pragma unroll
            for (int j = 0; j < 4; j++)
#pragma unroll
                for (int r = 0; r < 4; r++) {
                    int row = m0 + wr + i * 16 + quad * 4 + r;
                    int col = n0 + wc + j * 16 + ln;
                    Cm[(size_t)row * N + col] = f2bf(acc[i][j][r]);
                }
    }
}

// ---------------- O-proj GEMM: out = Ob @ Wo^T, fp32 out; z>0 dups -----------
__global__ __launch_bounds__(256, 4) void gemm_out(
    const u16* __restrict__ A, const u16* __restrict__ B,
    float* __restrict__ C, float* __restrict__ Cdummy)
{
    __shared__ u16 lA[64 * 32];
    __shared__ u16 lB[128 * 32];
    const int K = DM, N = DM;
    int m0 = blockIdx.y * 64, n0 = blockIdx.x * 128;
    float* Cd = blockIdx.z ? Cdummy : C;
    int tid = threadIdx.x;
    int wave = tid >> 6, lane = tid & 63, ln = lane & 15, quad = lane >> 4;
    int wr2 = (wave >> 1) * 32, wc2 = (wave & 1) * 64;

    f32x4 acc[2][4];
#pragma unroll
    for (int i = 0; i < 2; i++)
#pragma unroll
        for (int j = 0; j < 4; j++)
#pragma unroll
            for (int r = 0; r < 4; r++) acc[i][j][r] = 0.f;

    int scol = (lane & 3) * 8;
    int arow = wave * 16 + (lane >> 2);
    const u16* gA0 = &A[(size_t)(m0 + arow) * K + scol];
    int brow = wave * 32 + (lane >> 2);
    const u16* gB0 = &B[(size_t)(n0 + brow) * K + scol];
    const u16* gB1 = &B[(size_t)(n0 + brow + 16) * K + scol];
    u16* dA0 = &lA[(wave * 16) * 32];
    u16* dB0 = &lB[(wave * 32) * 32];
    u16* dB1 = &lB[(wave * 32 + 16) * 32];

    for (int kk0 = 0; kk0 < K / 32; kk0++) {
        __syncthreads();
        GLOAD_LDS16(gA0, dA0);
        GLOAD_LDS16(gB0, dB0);
        GLOAD_LDS16(gB1, dB1);
        gA0 += 32; gB0 += 32; gB1 += 32;
        __syncthreads();
        bf16x8 af[2], bfr[4];
#pragma unroll
        for (int i = 0; i < 2; i++) af[i]  = *(const bf16x8*)(&lA[(wr2 + i * 16 + ln) * 32 + quad * 8]);
#pragma unroll
        for (int j = 0; j < 4; j++) bfr[j] = *(const bf16x8*)(&lB[(wc2 + j * 16 + ln) * 32 + quad * 8]);
#pragma unroll
        for (int i = 0; i < 2; i++)
#pragma unroll
            for (int j = 0; j < 4; j++)
                acc[i][j] = __builtin_amdgcn_mfma_f32_16x16x32_bf16(af[i], bfr[j], acc[i][j], 0, 0, 0);
    }

#pragma unroll
    for (int i = 0; i < 2; i++)
#pragma unroll
        for (int j = 0; j < 4; j++)
#pragma unroll
            for (int r = 0; r < 4; r++) {
                int row = m0 + wr2 + i * 16 + quad * 4 + r;
                int col = n0 + wc2 + j * 16 + ln;
                Cd[(size_t)row * N + col] = acc[i][j][r];
            }
}

// ---------------- flash attention with forget-gate decay; y>=32 dups ---------
__global__ __launch_bounds__(256, 3) void attn_fox(
    const u16* __restrict__ Q, const u16* __restrict__ K,
    const u16* __restrict__ Vt, const float* __restrict__ F,
    u16* __restrict__ O, u16* __restrict__ Odummy)
{
    __shared__ u16 lP[4 * 16 * 72];    // per-wave 16x64 P strip, padded

    int h = blockIdx.y & 31;
    int dup = blockIdx.y >> 5;
    u16* Od = dup ? Odummy : O;
    int q0 = blockIdx.x * 64;
    int tid = threadIdx.x;
    int wave = tid >> 6, lane = tid & 63, ln = lane & 15, quad = lane >> 4;
    const float scale = 0.125f;        // HD^-0.5
    const float* Fh = F + (size_t)h * SEQ;

    bf16x8 aq[2];
    int qrow = q0 + wave * 16 + ln;
#pragma unroll
    for (int kk = 0; kk < 2; kk++)
        aq[kk] = *(const bf16x8*)(&Q[(size_t)qrow * DM + h * HDIM + kk * 32 + quad * 8]);

    float fq[4];
#pragma unroll
    for (int r = 0; r < 4; r++) fq[r] = Fh[q0 + wave * 16 + quad * 4 + r];

    float m_run[4], l_run[4];
    f32x4 o_acc[4];
#pragma unroll
    for (int r = 0; r < 4; r++) { m_run[r] = -1e30f; l_run[r] = 0.f; }
#pragma unroll
    for (int jo = 0; jo < 4; jo++)
#pragma unroll
        for (int r = 0; r < 4; r++) o_acc[jo][r] = 0.f;

    float Fq0 = Fh[q0];
    int nt = q0 / 64 + 1;
    u16* lPw = &lP[wave * 16 * 72];

    int kt0 = 0;
    {
        int lo = 0, hi = nt - 1;       // diag tile always live
        while (lo < hi) {
            int mid = (lo + hi) >> 1;
            if (Fq0 - Fh[mid * 64 + 63] >= -50.f) hi = mid; else lo = mid + 1;
        }
        kt0 = lo;
    }

    for (int kt = kt0; kt < nt; kt++) {
        int kb = kt * 64;

        f32x4 s_acc[4];
#pragma unroll
        for (int j = 0; j < 4; j++)
#pragma unroll
            for (int r = 0; r < 4; r++) s_acc[j][r] = 0.f;
#pragma unroll
        for (int kk = 0; kk < 2; kk++)
#pragma unroll
            for (int j = 0; j < 4; j++) {
                bf16x8 bk = *(const bf16x8*)(&K[(size_t)(kb + j * 16 + ln) * DM + h * HDIM + kk * 32 + quad * 8]);
                s_acc[j] = __builtin_amdgcn_mfma_f32_16x16x32_bf16(aq[kk], bk, s_acc[j], 0, 0, 0);
            }

        bool diag = (kt == nt - 1);
        int qbase = q0 + wave * 16 + quad * 4;
        float vv[4][4];
        float m_new[4];
#pragma unroll
        for (int r = 0; r < 4; r++) m_new[r] = -1e30f;
#pragma unroll
        for (int j = 0; j < 4; j++) {
            float fk = Fh[kb + j * 16 + ln];
            int kglob = kb + j * 16 + ln;
#pragma unroll
            for (int r = 0; r < 4; r++) {
                float v = s_acc[j][r] * scale + (fq[r] - fk);
                if (diag && kglob > qbase + r) v = -1e30f;
                vv[j][r] = v;
                m_new[r] = fmaxf(m_new[r], v);
            }
        }
#pragma unroll
        for (int r = 0; r < 4; r++) {
#pragma unroll
            for (int m = 1; m < 16; m <<= 1) m_new[r] = fmaxf(m_new[r], __shfl_xor(m_new[r], m));
        }
        float alpha[4];
#pragma unroll
        for (int r = 0; r < 4; r++) {
            float mt = fmaxf(m_run[r], m_new[r]);
            alpha[r] = expf(m_run[r] - mt);
            m_run[r] = mt;
        }
        float lsum[4] = {0.f, 0.f, 0.f, 0.f};
#pragma unroll
        for (int j = 0; j < 4; j++)
#pragma unroll
            for (int r = 0; r < 4; r++) {
                float pv = expf(vv[j][r] - m_run[r]);
                vv[j][r] = pv;
                lsum[r] += pv;
            }
#pragma unroll
        for (int r = 0; r < 4; r++) {
#pragma unroll
            for (int m = 1; m < 16; m <<= 1) lsum[r] += __shfl_xor(lsum[r], m);
            l_run[r] = l_run[r] * alpha[r] + lsum[r];
        }
#pragma unroll
        for (int jo = 0; jo < 4; jo++)
#pragma unroll
            for (int r = 0; r < 4; r++) o_acc[jo][r] *= alpha[r];

#pragma unroll
        for (int j = 0; j < 4; j++)
#pragma unroll
            for (int r = 0; r < 4; r++)
                lPw[(quad * 4 + r) * 72 + j * 16 + ln] = f2bf(vv[j][r]);
        __syncthreads();
        bf16x8 ap[2];
#pragma unroll
        for (int kk = 0; kk < 2; kk++)
            ap[kk] = *(const bf16x8*)(&lPw[ln * 72 + kk * 32 + quad * 8]);

#pragma unroll
        for (int kk = 0; kk < 2; kk++)
#pragma unroll
            for (int jo = 0; jo < 4; jo++) {
                bf16x8 bv = *(const bf16x8*)(&Vt[(size_t)(h * HDIM + jo * 16 + ln) * SEQ + kb + kk * 32 + quad * 8]);
                o_acc[jo] = __builtin_amdgcn_mfma_f32_16x16x32_bf16(ap[kk], bv, o_acc[jo], 0, 0, 0);
            }
    }

#pragma unroll
    for (int r = 0; r < 4; r++) {
        float inv = 1.f / l_run[r];
        int row = q0 + wave * 16 + quad * 4 + r;
#pragma unroll
        for (int jo = 0; jo < 4; jo++)
            Od[(size_t)row * DM + h * HDIM + jo * 16 + ln] = f2bf(o_acc[jo][r] * inv);
    }
}

// ------------------------------------------------------------------------------
extern "C" void kernel_launch(void* const* d_in, const int* in_sizes, int n_in,
                              void* d_out, int out_size, void* d_ws, size_t ws_size,
                              hipStream_t stream)
{
    const float* X   = (const float*)d_in[0];
    const float* Wq  = (const float*)d_in[1];
    const float* Wk  = (const float*)d_in[2];
    const float* Wv  = (const float*)d_in[3];
    const float* Wf  = (const float*)d_in[4];
    const float* bfp = (const float*)d_in[5];
    const float* Wo  = (const float*)d_in[6];
    float* out = (float*)d_out;

    char* ws = (char*)d_ws;
    const size_t MB8 = (size_t)DM * SEQ * 2;  // 8 MiB per bf16 2048x2048
    u16* Xb  = (u16*)(ws + 0 * MB8);
    u16* Wqb = (u16*)(ws + 1 * MB8);
    u16* Wkb = (u16*)(ws + 2 * MB8);
    u16* Wvb = (u16*)(ws + 3 * MB8);
    u16* Wob = (u16*)(ws + 4 * MB8);
    u16* Qb  = (u16*)(ws + 5 * MB8);
    u16* Kb  = (u16*)(ws + 6 * MB8);
    u16* Vtb = (u16*)(ws + 7 * MB8);          // V transposed [d2][s]
    u16* Ob  = (u16*)(ws + 8 * MB8);
    float* Fb = (float*)(ws + 9 * MB8);       // 32*2048 fp32 = 256 KiB
    float* Fpart = (float*)(ws + 8 * MB8);    // aliases Ob (dead until attn)
    // Dead-scratch dup destinations (measurement round only):
    u16*   cvtDummy  = Qb;                        // overwritten by gemm_qkv
    float* gatesDummy= (float*)(ws + 8 * MB8 + 4 * 1024 * 1024); // Ob 2nd half
    u16*   attnDummy = Xb;                        // dead after gemm_qkv
    float* outDummy  = (float*)Wqb;               // Wqb+Wkb dead after gemm_qkv

    cvt_bf16<<<dim3(1024, 5, 3), dim3(256), 0, stream>>>(X, Wq, Wk, Wv, Wo, Xb, Wqb, Wkb, Wvb, Wob, cvtDummy);
    gates_gemm<<<dim3(32, 16, 2), dim3(256), 0, stream>>>(X, Wf, Fpart, gatesDummy);
    gates_scan<<<dim3(NH), dim3(256), 0, stream>>>(Fpart, Fb, bfp);
    gemm_qkv<<<dim3(16, 16, 3), dim3(256), 0, stream>>>(Xb, Wqb, Wkb, Wvb, Qb, Kb, Vtb);
    attn_fox<<<dim3(SEQ / 64, NH * 5), dim3(256), 0, stream>>>(Qb, Kb, Vtb, Fb, Ob, attnDummy);
    gemm_out<<<dim3(16, 32, 3), dim3(256), 0, stream>>>(Ob, Wob, out, outDummy);
}

// Round 8
// 272.551 us; speedup vs baseline: 1.6642x; 1.6642x over previous
//
#include <hip/hip_runtime.h>
#include <stdint.h>

#define SEQ 2048
#define DM  2048
#define NH  32
#define HDIM 64

typedef unsigned short u16;
typedef short bf16x8 __attribute__((ext_vector_type(8)));
typedef float f32x4 __attribute__((ext_vector_type(4)));

__device__ __forceinline__ u16 f2bf(float f) {
    union { float f; uint32_t u; } v; v.f = f;
    uint32_t u = v.u;
    uint32_t r = (u + 0x7fffu + ((u >> 16) & 1u)) >> 16;
    return (u16)r;
}

// async global->LDS, 16B per lane. LDS dest is wave-uniform base + lane*16.
#define GLOAD_LDS16(g, l) __builtin_amdgcn_global_load_lds( \
    (const __attribute__((address_space(1))) uint32_t*)(g), \
    (__attribute__((address_space(3))) uint32_t*)(l), 16, 0, 0)

// ---------------- prep: cvt (blocks 0..5119) + gates GEMM (5120..5631) --------
// Fat-kernel merge: both halves depend only on kernel inputs (X, W*), no
// intra-kernel ordering assumed. Cuts one dispatch boundary.
__global__ __launch_bounds__(256) void prep(
    const float* __restrict__ X, const float* __restrict__ Wq,
    const float* __restrict__ Wk, const float* __restrict__ Wv,
    const float* __restrict__ Wo, const float* __restrict__ Wf,
    u16* __restrict__ Xb, u16* __restrict__ Wqb, u16* __restrict__ Wkb,
    u16* __restrict__ Wvb, u16* __restrict__ Wob, float* __restrict__ Fpart)
{
    __shared__ float lsh[64 * 68 + 32 * 68];
    int bid = blockIdx.x;
    int tid = threadIdx.x;
    if (bid < 5120) {
        // ---- cvt: fp32 -> bf16, array = bid>>10, 1024 blocks each ----
        const int NV = (DM * SEQ) / 4;
        int arr = bid >> 10, bx = bid & 1023;
        const float4* s; u16* d;
        switch (arr) {
            case 0:  s = (const float4*)X;  d = Xb;  break;
            case 1:  s = (const float4*)Wq; d = Wqb; break;
            case 2:  s = (const float4*)Wk; d = Wkb; break;
            case 3:  s = (const float4*)Wv; d = Wvb; break;
            default: s = (const float4*)Wo; d = Wob; break;
        }
        for (int i = bx * 256 + tid; i < NV; i += 1024 * 256) {
            float4 v = s[i];
            ushort4 o;
            o.x = f2bf(v.x); o.y = f2bf(v.y); o.z = f2bf(v.z); o.w = f2bf(v.w);
            *(ushort4*)(d + i * 4) = o;
        }
    } else {
        // ---- gates: Fpart[kp][h][s] = X[s, kp-part] . Wf[h, kp-part] ----
        float* lX = lsh;                 // [64][68]
        float* lW = lsh + 64 * 68;       // [32][68]
        int g = bid - 5120;
        int s0 = (g & 31) * 64;
        int kp = g >> 5;                 // 0..15
        int h = tid & 31, sg = tid >> 5;
        float acc[8] = {0.f,0.f,0.f,0.f,0.f,0.f,0.f,0.f};
        for (int k0 = kp * 128; k0 < kp * 128 + 128; k0 += 64) {
            __syncthreads();
            {
                int r = tid >> 2, seg = tid & 3;
                const float4* src = (const float4*)(X + (size_t)(s0 + r) * DM + k0);
                float4* dst = (float4*)(&lX[r * 68]);
#pragma unroll
                for (int i = 0; i < 4; i++) dst[seg + 4 * i] = src[seg + 4 * i];
#pragma unroll
                for (int j = 0; j < 2; j++) {
                    int ii = tid + j * 256;
                    int wr_ = ii >> 4, wc_ = ii & 15;
                    ((float4*)(&lW[wr_ * 68]))[wc_] =
                        ((const float4*)(Wf + (size_t)wr_ * DM + k0))[wc_];
                }
            }
            __syncthreads();
#pragma unroll
            for (int k4 = 0; k4 < 16; k4++) {
                float4 w = ((const float4*)(&lW[h * 68]))[k4];
#pragma unroll
                for (int i = 0; i < 8; i++) {
                    float4 x = ((const float4*)(&lX[(sg + 8 * i) * 68]))[k4];
                    acc[i] += x.x * w.x + x.y * w.y + x.z * w.z + x.w * w.w;
                }
            }
        }
#pragma unroll
        for (int i = 0; i < 8; i++)
            Fpart[(size_t)kp * NH * SEQ + h * SEQ + s0 + sg + 8 * i] = acc[i];
    }
}

// ---------------- QKV GEMM (z<3) + gates_scan (z==3, first 32 blocks) --------
// z==2 (V) writes TRANSPOSED output Vt[d2][s]. Scan depends only on prep's
// Fpart (same dependency level as qkv's inputs) -> safe fat-kernel merge.
__global__ __launch_bounds__(256, 3) void gemm_qkv(
    const u16* __restrict__ A,
    const u16* __restrict__ B0, const u16* __restrict__ B1, const u16* __restrict__ B2,
    u16* __restrict__ C0, u16* __restrict__ C1, u16* __restrict__ C2,
    const float* __restrict__ Fpart, float* __restrict__ F,
    const float* __restrict__ bfp)
{
    __shared__ u16 lA[128 * 32];
    __shared__ u16 lB[128 * 32];
    const int K = DM, N = DM;
    int z = blockIdx.z;
    int tid = threadIdx.x;

    if (z == 3) {
        // ---- gates_scan: reduce k-partials, logsigmoid(+bias), cumsum ----
        int flat = blockIdx.y * 16 + blockIdx.x;
        if (flat >= NH) return;
        int h = flat;
        float* lws = (float*)lA;
        int lane = tid & 63, wv = tid >> 6;
        float bb = bfp[h];
        float v[8] = {0.f,0.f,0.f,0.f,0.f,0.f,0.f,0.f};
#pragma unroll
        for (int kp = 0; kp < 16; kp++) {
            const float4* src = (const float4*)(Fpart + (size_t)kp * NH * SEQ + (size_t)h * SEQ);
            float4 a = src[tid * 2], b2 = src[tid * 2 + 1];
            v[0] += a.x;  v[1] += a.y;  v[2] += a.z;  v[3] += a.w;
            v[4] += b2.x; v[5] += b2.y; v[6] += b2.z; v[7] += b2.w;
        }
#pragma unroll
        for (int i = 0; i < 8; i++) {
            float g = v[i] + bb;
            v[i] = fminf(g, 0.f) - log1pf(expf(-fabsf(g)));
        }
#pragma unroll
        for (int i = 1; i < 8; i++) v[i] += v[i - 1];
        float tsum = v[7];
        float sc = tsum;
#pragma unroll
        for (int d = 1; d < 64; d <<= 1) {
            float t = __shfl_up(sc, d);
            if (lane >= d) sc += t;
        }
        if (lane == 63) lws[wv] = sc;
        __syncthreads();
        float woff = 0.f;
#pragma unroll
        for (int w2 = 0; w2 < 4; w2++) if (w2 < wv) woff += lws[w2];
        float off = woff + sc - tsum;
#pragma unroll
        for (int i = 0; i < 8; i++) v[i] += off;
        float4 o1 = {v[0], v[1], v[2], v[3]}, o2 = {v[4], v[5], v[6], v[7]};
        ((float4*)(F + (size_t)h * SEQ))[tid * 2] = o1;
        ((float4*)(F + (size_t)h * SEQ))[tid * 2 + 1] = o2;
        return;
    }

    const u16* Bm = (z == 0) ? B0 : ((z == 1) ? B1 : B2);
    u16* Cm = (z == 0) ? C0 : ((z == 1) ? C1 : C2);
    int m0 = blockIdx.y * 128, n0 = blockIdx.x * 128;
    int wave = tid >> 6, lane = tid & 63, ln = lane & 15, quad = lane >> 4;
    int wr = (wave >> 1) * 64, wc = (wave & 1) * 64;

    f32x4 acc[4][4];
#pragma unroll
    for (int i = 0; i < 4; i++)
#pragma unroll
        for (int j = 0; j < 4; j++)
#pragma unroll
            for (int r = 0; r < 4; r++) acc[i][j][r] = 0.f;

    int srow = wave * 32 + (lane >> 2);
    int scol = (lane & 3) * 8;
    const u16* gA0 = &A[(size_t)(m0 + srow) * K + scol];
    const u16* gA1 = &A[(size_t)(m0 + srow + 16) * K + scol];
    const u16* gB0 = &Bm[(size_t)(n0 + srow) * K + scol];
    const u16* gB1 = &Bm[(size_t)(n0 + srow + 16) * K + scol];
    u16* dA0 = &lA[(wave * 32) * 32];
    u16* dA1 = &lA[(wave * 32 + 16) * 32];
    u16* dB0 = &lB[(wave * 32) * 32];
    u16* dB1 = &lB[(wave * 32 + 16) * 32];

    for (int kk0 = 0; kk0 < K / 32; kk0++) {
        __syncthreads();
        GLOAD_LDS16(gA0, dA0);
        GLOAD_LDS16(gA1, dA1);
        GLOAD_LDS16(gB0, dB0);
        GLOAD_LDS16(gB1, dB1);
        gA0 += 32; gA1 += 32; gB0 += 32; gB1 += 32;
        __syncthreads();
        bf16x8 af[4], bfr[4];
#pragma unroll
        for (int i = 0; i < 4; i++) af[i]  = *(const bf16x8*)(&lA[(wr + i * 16 + ln) * 32 + quad * 8]);
#pragma unroll
        for (int j = 0; j < 4; j++) bfr[j] = *(const bf16x8*)(&lB[(wc + j * 16 + ln) * 32 + quad * 8]);
#pragma unroll
        for (int i = 0; i < 4; i++)
#pragma unroll
            for (int j = 0; j < 4; j++)
                acc[i][j] = __builtin_amdgcn_mfma_f32_16x16x32_bf16(af[i], bfr[j], acc[i][j], 0, 0, 0);
    }

    if (z == 2) {
#pragma unroll
        for (int i = 0; i < 4; i++)
#pragma unroll
            for (int j = 0; j < 4; j++) {
                int col = n0 + wc + j * 16 + ln;
                int row0 = m0 + wr + i * 16 + quad * 4;
                ushort4 pk;
                pk.x = f2bf(acc[i][j][0]); pk.y = f2bf(acc[i][j][1]);
                pk.z = f2bf(acc[i][j][2]); pk.w = f2bf(acc[i][j][3]);
                *(ushort4*)(&Cm[(size_t)col * SEQ + row0]) = pk;
            }
    } else {
#pragma unroll
        for (int i = 0; i < 4; i++)
#pragma unroll
            for (int j = 0; j < 4; j++)
#pragma unroll
                for (int r = 0; r < 4; r++) {
                    int row = m0 + wr + i * 16 + quad * 4 + r;
                    int col = n0 + wc + j * 16 + ln;
                    Cm[(size_t)row * N + col] = f2bf(acc[i][j][r]);
                }
    }
}

// ---------------- O-proj GEMM: out[m][n] = sum_k Ob[m][k] * Wo[n][k], fp32 out
__global__ __launch_bounds__(256, 4) void gemm_out(
    const u16* __restrict__ A, const u16* __restrict__ B,
    float* __restrict__ C)
{
    __shared__ u16 lA[64 * 32];
    __shared__ u16 lB[128 * 32];
    const int K = DM, N = DM;
    int m0 = blockIdx.y * 64, n0 = blockIdx.x * 128;
    int tid = threadIdx.x;
    int wave = tid >> 6, lane = tid & 63, ln = lane & 15, quad = lane >> 4;
    int wr2 = (wave >> 1) * 32, wc2 = (wave & 1) * 64;

    f32x4 acc[2][4];
#pragma unroll
    for (int i = 0; i < 2; i++)
#pragma unroll
        for (int j = 0; j < 4; j++)
#pragma unroll
            for (int r = 0; r < 4; r++) acc[i][j][r] = 0.f;

    int scol = (lane & 3) * 8;
    int arow = wave * 16 + (lane >> 2);
    const u16* gA0 = &A[(size_t)(m0 + arow) * K + scol];
    int brow = wave * 32 + (lane >> 2);
    const u16* gB0 = &B[(size_t)(n0 + brow) * K + scol];
    const u16* gB1 = &B[(size_t)(n0 + brow + 16) * K + scol];
    u16* dA0 = &lA[(wave * 16) * 32];
    u16* dB0 = &lB[(wave * 32) * 32];
    u16* dB1 = &lB[(wave * 32 + 16) * 32];

    for (int kk0 = 0; kk0 < K / 32; kk0++) {
        __syncthreads();
        GLOAD_LDS16(gA0, dA0);
        GLOAD_LDS16(gB0, dB0);
        GLOAD_LDS16(gB1, dB1);
        gA0 += 32; gB0 += 32; gB1 += 32;
        __syncthreads();
        bf16x8 af[2], bfr[4];
#pragma unroll
        for (int i = 0; i < 2; i++) af[i]  = *(const bf16x8*)(&lA[(wr2 + i * 16 + ln) * 32 + quad * 8]);
#pragma unroll
        for (int j = 0; j < 4; j++) bfr[j] = *(const bf16x8*)(&lB[(wc2 + j * 16 + ln) * 32 + quad * 8]);
#pragma unroll
        for (int i = 0; i < 2; i++)
#pragma unroll
            for (int j = 0; j < 4; j++)
                acc[i][j] = __builtin_amdgcn_mfma_f32_16x16x32_bf16(af[i], bfr[j], acc[i][j], 0, 0, 0);
    }

#pragma unroll
    for (int i = 0; i < 2; i++)
#pragma unroll
        for (int j = 0; j < 4; j++)
#pragma unroll
            for (int r = 0; r < 4; r++) {
                int row = m0 + wr2 + i * 16 + quad * 4 + r;
                int col = n0 + wc2 + j * 16 + ln;
                C[(size_t)row * N + col] = acc[i][j][r];
            }
}

// ---------------- flash attention with forget-gate decay ----------------------
__global__ __launch_bounds__(256, 3) void attn_fox(
    const u16* __restrict__ Q, const u16* __restrict__ K,
    const u16* __restrict__ Vt, const float* __restrict__ F,
    u16* __restrict__ O)
{
    __shared__ u16 lP[4 * 16 * 72];    // per-wave 16x64 P strip, padded

    int h = blockIdx.y;
    int q0 = blockIdx.x * 64;
    int tid = threadIdx.x;
    int wave = tid >> 6, lane = tid & 63, ln = lane & 15, quad = lane >> 4;
    const float scale = 0.125f;        // HD^-0.5
    const float* Fh = F + (size_t)h * SEQ;

    bf16x8 aq[2];
    int qrow = q0 + wave * 16 + ln;
#pragma unroll
    for (int kk = 0; kk < 2; kk++)
        aq[kk] = *(const bf16x8*)(&Q[(size_t)qrow * DM + h * HDIM + kk * 32 + quad * 8]);

    float fq[4];
#pragma unroll
    for (int r = 0; r < 4; r++) fq[r] = Fh[q0 + wave * 16 + quad * 4 + r];

    float m_run[4], l_run[4];
    f32x4 o_acc[4];
#pragma unroll
    for (int r = 0; r < 4; r++) { m_run[r] = -1e30f; l_run[r] = 0.f; }
#pragma unroll
    for (int jo = 0; jo < 4; jo++)
#pragma unroll
        for (int r = 0; r < 4; r++) o_acc[jo][r] = 0.f;

    float Fq0 = Fh[q0];
    int nt = q0 / 64 + 1;
    u16* lPw = &lP[wave * 16 * 72];

    int kt0 = 0;
    {
        int lo = 0, hi = nt - 1;       // diag tile always live
        while (lo < hi) {
            int mid = (lo + hi) >> 1;
            if (Fq0 - Fh[mid * 64 + 63] >= -50.f) hi = mid; else lo = mid + 1;
        }
        kt0 = lo;
    }

    for (int kt = kt0; kt < nt; kt++) {
        int kb = kt * 64;

        f32x4 s_acc[4];
#pragma unroll
        for (int j = 0; j < 4; j++)
#pragma unroll
            for (int r = 0; r < 4; r++) s_acc[j][r] = 0.f;
#pragma unroll
        for (int kk = 0; kk < 2; kk++)
#pragma unroll
            for (int j = 0; j < 4; j++) {
                bf16x8 bk = *(const bf16x8*)(&K[(size_t)(kb + j * 16 + ln) * DM + h * HDIM + kk * 32 + quad * 8]);
                s_acc[j] = __builtin_amdgcn_mfma_f32_16x16x32_bf16(aq[kk], bk, s_acc[j], 0, 0, 0);
            }

        bool diag = (kt == nt - 1);
        int qbase = q0 + wave * 16 + quad * 4;
        float vv[4][4];
        float m_new[4];
#pragma unroll
        for (int r = 0; r < 4; r++) m_new[r] = -1e30f;
#pragma unroll
        for (int j = 0; j < 4; j++) {
            float fk = Fh[kb + j * 16 + ln];
            int kglob = kb + j * 16 + ln;
#pragma unroll
            for (int r = 0; r < 4; r++) {
                float v = s_acc[j][r] * scale + (fq[r] - fk);
                if (diag && kglob > qbase + r) v = -1e30f;
                vv[j][r] = v;
                m_new[r] = fmaxf(m_new[r], v);
            }
        }
#pragma unroll
        for (int r = 0; r < 4; r++) {
#pragma unroll
            for (int m = 1; m < 16; m <<= 1) m_new[r] = fmaxf(m_new[r], __shfl_xor(m_new[r], m));
        }
        float alpha[4];
#pragma unroll
        for (int r = 0; r < 4; r++) {
            float mt = fmaxf(m_run[r], m_new[r]);
            alpha[r] = expf(m_run[r] - mt);
            m_run[r] = mt;
        }
        float lsum[4] = {0.f, 0.f, 0.f, 0.f};
#pragma unroll
        for (int j = 0; j < 4; j++)
#pragma unroll
            for (int r = 0; r < 4; r++) {
                float pv = expf(vv[j][r] - m_run[r]);
                vv[j][r] = pv;
                lsum[r] += pv;
            }
#pragma unroll
        for (int r = 0; r < 4; r++) {
#pragma unroll
            for (int m = 1; m < 16; m <<= 1) lsum[r] += __shfl_xor(lsum[r], m);
            l_run[r] = l_run[r] * alpha[r] + lsum[r];
        }
#pragma unroll
        for (int jo = 0; jo < 4; jo++)
#pragma unroll
            for (int r = 0; r < 4; r++) o_acc[jo][r] *= alpha[r];

#pragma unroll
        for (int j = 0; j < 4; j++)
#pragma unroll
            for (int r = 0; r < 4; r++)
                lPw[(quad * 4 + r) * 72 + j * 16 + ln] = f2bf(vv[j][r]);
        __syncthreads();
        bf16x8 ap[2];
#pragma unroll
        for (int kk = 0; kk < 2; kk++)
            ap[kk] = *(const bf16x8*)(&lPw[ln * 72 + kk * 32 + quad * 8]);

#pragma unroll
        for (int kk = 0; kk < 2; kk++)
#pragma unroll
            for (int jo = 0; jo < 4; jo++) {
                bf16x8 bv = *(const bf16x8*)(&Vt[(size_t)(h * HDIM + jo * 16 + ln) * SEQ + kb + kk * 32 + quad * 8]);
                o_acc[jo] = __builtin_amdgcn_mfma_f32_16x16x32_bf16(ap[kk], bv, o_acc[jo], 0, 0, 0);
            }
    }

#pragma unroll
    for (int r = 0; r < 4; r++) {
        float inv = 1.f / l_run[r];
        int row = q0 + wave * 16 + quad * 4 + r;
#pragma unroll
        for (int jo = 0; jo < 4; jo++)
            O[(size_t)row * DM + h * HDIM + jo * 16 + ln] = f2bf(o_acc[jo][r] * inv);
    }
}

// ------------------------------------------------------------------------------
extern "C" void kernel_launch(void* const* d_in, const int* in_sizes, int n_in,
                              void* d_out, int out_size, void* d_ws, size_t ws_size,
                              hipStream_t stream)
{
    const float* X   = (const float*)d_in[0];
    const float* Wq  = (const float*)d_in[1];
    const float* Wk  = (const float*)d_in[2];
    const float* Wv  = (const float*)d_in[3];
    const float* Wf  = (const float*)d_in[4];
    const float* bfp = (const float*)d_in[5];
    const float* Wo  = (const float*)d_in[6];
    float* out = (float*)d_out;

    char* ws = (char*)d_ws;
    const size_t MB8 = (size_t)DM * SEQ * 2;  // 8 MiB per bf16 2048x2048
    u16* Xb  = (u16*)(ws + 0 * MB8);
    u16* Wqb = (u16*)(ws + 1 * MB8);
    u16* Wkb = (u16*)(ws + 2 * MB8);
    u16* Wvb = (u16*)(ws + 3 * MB8);
    u16* Wob = (u16*)(ws + 4 * MB8);
    u16* Qb  = (u16*)(ws + 5 * MB8);
    u16* Kb  = (u16*)(ws + 6 * MB8);
    u16* Vtb = (u16*)(ws + 7 * MB8);          // V transposed [d2][s]
    u16* Ob  = (u16*)(ws + 8 * MB8);
    float* Fb = (float*)(ws + 9 * MB8);       // 32*2048 fp32 = 256 KiB
    // gate k-partials (4 MiB) alias the Ob region: consumed by the scan slice
    // of gemm_qkv before attn_fox writes Ob (stream-ordered).
    float* Fpart = (float*)(ws + 8 * MB8);

    prep<<<dim3(5632), dim3(256), 0, stream>>>(X, Wq, Wk, Wv, Wo, Wf,
                                               Xb, Wqb, Wkb, Wvb, Wob, Fpart);
    gemm_qkv<<<dim3(16, 16, 4), dim3(256), 0, stream>>>(Xb, Wqb, Wkb, Wvb,
                                                        Qb, Kb, Vtb, Fpart, Fb, bfp);
    attn_fox<<<dim3(SEQ / 64, NH), dim3(256), 0, stream>>>(Qb, Kb, Vtb, Fb, Ob);
    gemm_out<<<dim3(16, 32), dim3(256), 0, stream>>>(Ob, Wob, out);
}